// Round 5
// baseline (327.951 us; speedup 1.0000x reference)
//
#include <hip/hip_runtime.h>

// ---------------------------------------------------------------------------
// PositionEncoder: per token (B*T = 262144), output 272 f32:
//   x[0:6] | emb[idx1] (128) | x[6:10] | emb[idx2] (128) | x[10:16]
// idx from matching (x[4],x[5]) / (x[8],x[9]) vs 26 nodes,
// close iff |p - node| <= 0.01 + 1e-5*|node| per dim; idx = first match + 1.
//
// R1: branchy per-element gather -> latency-bound, kernel ~145 us.
// R2: LDS output tile + coalesced float4 stream -> ~126 us.
// R4: nt stores: no change => RFO theory dead (fills get 6.3 TB/s with
//     FETCH~0 anyway). New theory: barrier-separated phases give the store
//     pipe a low duty cycle (block lifetime ~16 us for ~1.5 us of stores).
// R5: fill-style structure. K1 precomputes indices to ws; K2 is a barrier-
//     free, LDS-free grid-stride wave-task writer: each wave nt-stores one
//     contiguous half-row (552/536 B) as float2, sources lane-selected
//     between L2-hot emb row and the x pieces.
// ---------------------------------------------------------------------------

#define THREADS 256

typedef float vfloat2 __attribute__((ext_vector_type(2)));

constexpr float kNX[26] = {
    0.5454545454545454f, 0.6022727272727273f, 0.5454545454545454f,
    0.6022727272727273f, 0.4772727272727273f, 0.42045454545454547f,
    0.42045454545454547f, 0.4772727272727273f, 0.32954545454545453f,
    0.42045454545454547f, 0.4772727272727273f, 0.4772727272727273f,
    0.42045454545454547f, 0.32954545454545453f, 0.5727272727272728f,
    0.7613636363636364f, 0.8181818181818182f, 0.8181818181818182f,
    0.7613636363636364f, 0.7909090909090909f, 0.9431818181818182f,
    1.0f, 1.0f, 0.9431818181818182f, 0.9727272727272728f, 0.9727272727272728f};
constexpr float kNY[26] = {
    0.76f, 0.76f, 0.86f, 0.86f, 0.76f, 0.76f, 0.86f, 0.86f, 0.808f,
    0.48f, 0.48f, 0.38f, 0.38f, 0.428f, 0.62f, 0.76f, 0.76f, 0.86f,
    0.86f, 0.62f, 0.76f, 0.76f, 0.86f, 0.86f, 0.62f, 1.0f};

__device__ __forceinline__ int point_index(float px, float py) {
#pragma clang fp contract(off)
    int idx = 0;
    // Reverse iterate + overwrite => lowest-index match wins.
#pragma unroll
    for (int n = 25; n >= 0; --n) {
        float tx = 0.01f + 1.0e-5f * kNX[n];   // compile-time folded
        float ty = 0.01f + 1.0e-5f * kNY[n];
        bool c = (fabsf(px - kNX[n]) <= tx) && (fabsf(py - kNY[n]) <= ty);
        if (c) idx = n + 1;
    }
    return idx;
}

// ---- K1: one thread per token -> (idx1, idx2) into ws ---------------------
__global__ __launch_bounds__(THREADS) void idx_kernel(
    const float* __restrict__ x, int* __restrict__ wsi, int n_tokens) {
    int t = blockIdx.x * THREADS + threadIdx.x;
    if (t >= n_tokens) return;
    const float* xr = x + (size_t)t * 16;       // token row = one 64B line
    vfloat2 p1 = *(const vfloat2*)(xr + 4);     // 8B-aligned
    vfloat2 p2 = *(const vfloat2*)(xr + 8);
    int2 v = make_int2(point_index(p1.x, p1.y), point_index(p2.x, p2.y));
    ((int2*)wsi)[t] = v;                        // wsi[2t]=idx1, wsi[2t+1]=idx2
}

// ---- K2: grid-stride wave tasks; task = (token, half) ---------------------
// half 0 writes out cols [0,138):   x[0:6] | emb1[0:128] | x[6:10]
// half 1 writes out cols [138,272): emb2[0:128] | x[10:16]
// All stores are contiguous float2 nt within the task.
__global__ __launch_bounds__(THREADS) void write_kernel(
    const float* __restrict__ x, const float* __restrict__ emb,
    const int* __restrict__ wsi, float* __restrict__ out, int n_tokens) {
    const int lane = threadIdx.x & 63;
    const long long wave0  = ((long long)blockIdx.x * THREADS + threadIdx.x) >> 6;
    const long long nwaves = ((long long)gridDim.x * THREADS) >> 6;
    const long long n_tasks = 2LL * n_tokens;

    // nwaves is even => task parity is loop-invariant per wave (branch hoists)
    for (long long task = wave0; task < n_tasks; task += nwaves) {
        const int t   = (int)(task >> 1);
        const int idx = wsi[task];                   // broadcast (same addr)
        const float* xr = x + (size_t)t * 16;
        const float* er = emb + (size_t)idx * 128;   // L2-hot (51 KB table)
        if (((int)task & 1) == 0) {
            float* orow = out + (size_t)t * 272;     // 8B-aligned (+1088B rows)
            // slot L: cols [2L, 2L+2): L<3 -> x[2L..], else emb1[2L-6..]
            {
                const float* s = (lane < 3) ? (xr + 2 * lane)
                                            : (er + 2 * lane - 6);
                vfloat2 v = *(const vfloat2*)s;
                __builtin_nontemporal_store(v, (vfloat2*)(orow + 2 * lane));
            }
            // slots 64..68 by lanes 0..4: cols 128..137
            if (lane < 5) {
                int s2 = 64 + lane;
                const float* s = (lane < 3) ? (er + 2 * s2 - 6)    // emb1[122+2L]
                                            : (xr + 2 * s2 - 128); // x[6..9]
                vfloat2 v = *(const vfloat2*)s;
                __builtin_nontemporal_store(v, (vfloat2*)(orow + 2 * s2));
            }
        } else {
            float* orow = out + (size_t)t * 272 + 138;  // byte +552, 8B-aligned
            // slot L: cols [138+2L, 138+2L+2) from emb2[2L..]
            {
                vfloat2 v = *(const vfloat2*)(er + 2 * lane);
                __builtin_nontemporal_store(v, (vfloat2*)(orow + 2 * lane));
            }
            // slots 64..66 by lanes 0..2: cols 266..271 from x[10..15]
            if (lane < 3) {
                int s2 = 64 + lane;
                vfloat2 v = *(const vfloat2*)(xr + 10 + 2 * lane);
                __builtin_nontemporal_store(v, (vfloat2*)(orow + 2 * s2));
            }
        }
    }
}

extern "C" void kernel_launch(void* const* d_in, const int* in_sizes, int n_in,
                              void* d_out, int out_size, void* d_ws, size_t ws_size,
                              hipStream_t stream) {
    const float* x   = (const float*)d_in[0];   // [B, T, 16] f32
    const float* emb = (const float*)d_in[1];   // [100, 128] f32
    float* out = (float*)d_out;                 // [B, T, 272] f32
    int* wsi = (int*)d_ws;                      // [n_tokens] int2

    int n_tokens = in_sizes[0] / 16;            // 262144

    int b1 = (n_tokens + THREADS - 1) / THREADS;
    idx_kernel<<<b1, THREADS, 0, stream>>>(x, wsi, n_tokens);

    // 8192 blocks * 4 waves = 32768 waves; 524288 tasks -> 16 iters/wave
    write_kernel<<<8192, THREADS, 0, stream>>>(x, emb, wsi, out, n_tokens);
}

// Round 6
// 308.275 us; speedup vs baseline: 1.0638x; 1.0638x over previous
//
#include <hip/hip_runtime.h>

// ---------------------------------------------------------------------------
// PositionEncoder: per token (B*T = 262144), output 272 f32:
//   x[0:6] | emb[idx1] (128) | x[6:10] | emb[idx2] (128) | x[10:16]
// idx from matching (x[4],x[5]) / (x[8],x[9]) vs 26 nodes,
// close iff |p - node| <= 0.01 + 1e-5*|node| per dim; idx = first match + 1.
//
// R1 branchy gather ~145us; R2 LDS tile ~126us; R4 +nt ~122us (RFO theory
// dead); R5 half-row wave tasks ~150us (regressed: 8B stores + wsi->emb->st
// chain serializes on shared vmcnt).
// R6: one wave per token, 32 tokens/wave, no LDS/barriers. All region
// boundaries are even => a lane's two 8B chunks never straddle a region:
// each chunk = one f2 load from a cndmask-selected base (emb L2-hot),
// merged into ONE aligned 16B nt store (+1 predicated store, lanes 0-3).
// wsi via readfirstlane -> s_load (lgkmcnt; keeps vmcnt free for stores).
// ---------------------------------------------------------------------------

#define THREADS 256
#define TOK_PER_WAVE 32

typedef float vf2 __attribute__((ext_vector_type(2)));
typedef float vf4 __attribute__((ext_vector_type(4)));

constexpr float kNX[26] = {
    0.5454545454545454f, 0.6022727272727273f, 0.5454545454545454f,
    0.6022727272727273f, 0.4772727272727273f, 0.42045454545454547f,
    0.42045454545454547f, 0.4772727272727273f, 0.32954545454545453f,
    0.42045454545454547f, 0.4772727272727273f, 0.4772727272727273f,
    0.42045454545454547f, 0.32954545454545453f, 0.5727272727272728f,
    0.7613636363636364f, 0.8181818181818182f, 0.8181818181818182f,
    0.7613636363636364f, 0.7909090909090909f, 0.9431818181818182f,
    1.0f, 1.0f, 0.9431818181818182f, 0.9727272727272728f, 0.9727272727272728f};
constexpr float kNY[26] = {
    0.76f, 0.76f, 0.86f, 0.86f, 0.76f, 0.76f, 0.86f, 0.86f, 0.808f,
    0.48f, 0.48f, 0.38f, 0.38f, 0.428f, 0.62f, 0.76f, 0.76f, 0.86f,
    0.86f, 0.62f, 0.76f, 0.76f, 0.86f, 0.86f, 0.62f, 1.0f};

__device__ __forceinline__ int point_index(float px, float py) {
#pragma clang fp contract(off)
    int idx = 0;
    // Reverse iterate + overwrite => lowest-index match wins.
#pragma unroll
    for (int n = 25; n >= 0; --n) {
        float tx = 0.01f + 1.0e-5f * kNX[n];   // compile-time folded
        float ty = 0.01f + 1.0e-5f * kNY[n];
        bool c = (fabsf(px - kNX[n]) <= tx) && (fabsf(py - kNY[n]) <= ty);
        if (c) idx = n + 1;
    }
    return idx;
}

// ---- K1: one thread per token -> (idx1, idx2) into ws ---------------------
__global__ __launch_bounds__(THREADS) void idx_kernel(
    const float* __restrict__ x, int* __restrict__ wsi, int n_tokens) {
    int t = blockIdx.x * THREADS + threadIdx.x;
    if (t >= n_tokens) return;
    const float* xr = x + (size_t)t * 16;
    vf2 p1 = *(const vf2*)(xr + 4);
    vf2 p2 = *(const vf2*)(xr + 8);
    ((int2*)wsi)[t] = make_int2(point_index(p1.x, p1.y),
                                point_index(p2.x, p2.y));
}

// chunk source: 2-col chunk starting at even col c never straddles a region
__device__ __forceinline__ const float* chunk_src(
    int c, const float* xr, const float* e1, const float* e2) {
    const float* p = xr + c;                 // c in [0,6)
    p = (c >= 6)   ? e1 + (c - 6)   : p;     // [6,134)   emb row 1
    p = (c >= 134) ? xr + (c - 128) : p;     // [134,138) x[6:10]
    p = (c >= 138) ? e2 + (c - 138) : p;     // [138,266) emb row 2
    p = (c >= 266) ? xr + (c - 256) : p;     // [266,272) x[10:16]
    return p;
}

// ---- K2: one wave per token; wave handles 32 consecutive tokens -----------
__global__ __launch_bounds__(THREADS) void write_kernel(
    const float* __restrict__ x, const float* __restrict__ emb,
    const int* __restrict__ wsi, float* __restrict__ out, int n_tokens) {
    const int lane = threadIdx.x & 63;
    const int wave = blockIdx.x * (THREADS / 64) + (threadIdx.x >> 6);
    const int c0   = 4 * lane;          // store 1: cols [c0, c0+4)
    const int cs   = 256 + 4 * lane;    // store 2 (lanes 0-3): [cs, cs+4)

    const int t0 = wave * TOK_PER_WAVE;

#pragma unroll 4
    for (int it = 0; it < TOK_PER_WAVE; ++it) {
        int t = t0 + it;
        if (t >= n_tokens) break;
        int ts = __builtin_amdgcn_readfirstlane(t);     // force scalar path
        int2 id = ((const int2*)wsi)[ts];               // s_load_dwordx2
        const float* xr = x   + (size_t)ts * 16;
        const float* e1 = emb + (size_t)id.x * 128;     // L2-hot (51 KB)
        const float* e2 = emb + (size_t)id.y * 128;
        float* orow = out + (size_t)ts * 272;

        // store 1: 64 lanes cover cols [0,256) as one 16B nt store each
        vf2 a = *(const vf2*)chunk_src(c0,     xr, e1, e2);
        vf2 b = *(const vf2*)chunk_src(c0 + 2, xr, e1, e2);
        vf4 v;  v.x = a.x; v.y = a.y; v.z = b.x; v.w = b.y;
        __builtin_nontemporal_store(v, (vf4*)(orow + c0));

        // store 2: lanes 0-3 cover cols [256,272)
        if (lane < 4) {
            vf2 a2 = *(const vf2*)chunk_src(cs,     xr, e1, e2);
            vf2 b2 = *(const vf2*)chunk_src(cs + 2, xr, e1, e2);
            vf4 v2;  v2.x = a2.x; v2.y = a2.y; v2.z = b2.x; v2.w = b2.y;
            __builtin_nontemporal_store(v2, (vf4*)(orow + cs));
        }
    }
}

extern "C" void kernel_launch(void* const* d_in, const int* in_sizes, int n_in,
                              void* d_out, int out_size, void* d_ws, size_t ws_size,
                              hipStream_t stream) {
    const float* x   = (const float*)d_in[0];   // [B, T, 16] f32
    const float* emb = (const float*)d_in[1];   // [100, 128] f32
    float* out = (float*)d_out;                 // [B, T, 272] f32
    int* wsi = (int*)d_ws;                      // [n_tokens] int2

    int n_tokens = in_sizes[0] / 16;            // 262144

    int b1 = (n_tokens + THREADS - 1) / THREADS;
    idx_kernel<<<b1, THREADS, 0, stream>>>(x, wsi, n_tokens);

    // one wave per 32 tokens: 8192 waves = 2048 blocks of 4 waves
    int waves  = (n_tokens + TOK_PER_WAVE - 1) / TOK_PER_WAVE;
    int b2     = (waves + (THREADS / 64) - 1) / (THREADS / 64);
    write_kernel<<<b2, THREADS, 0, stream>>>(x, emb, wsi, out, n_tokens);
}